// Round 4
// baseline (100.173 us; speedup 1.0000x reference)
//
#include <hip/hip_runtime.h>
#include <hip/hip_cooperative_groups.h>
#include <math.h>

namespace cg = cooperative_groups;

#define NN 129
#define INC 129
#define OUTC 64
#define NE 4096
#define GRID_B 256
#define BLK 1024
#define NWB (BLK / 64)          // 16 waves per block
#define TOTW (GRID_B * NWB)     // 4096 waves

__device__ __forceinline__ float sigmf(float x) { return 1.0f / (1.0f + expf(-x)); }

__global__ __launch_bounds__(BLK, 4) void k_all(
    const float* __restrict__ x, const int* __restrict__ ei,
    const float* __restrict__ ew, const float* __restrict__ p,
    const float* __restrict__ W0, const float* __restrict__ w_ih,
    const float* __restrict__ w_hh, const float* __restrict__ b_ih,
    const float* __restrict__ b_hh, const float* __restrict__ cb,
    const float* __restrict__ lw, const float* __restrict__ lb,
    float* __restrict__ out, float* __restrict__ score,
    float* __restrict__ dis, float* __restrict__ W, float* __restrict__ agg)
{
    cg::grid_group grid = cg::this_grid();
    __shared__ float s_sc[NN];
    __shared__ int   s_perm[NN];
    __shared__ float s_a[NN];
    __shared__ float s_h[NN];

    const int t = threadIdx.x, b = blockIdx.x;
    const int wv = t >> 6, lane = t & 63;
    const int gw = b * NWB + wv;      // global wave id
    const int tg = b * BLK + t;       // global thread id
    const int* row = ei;              // edge_index[0]
    const int* col = ei + NE;         // edge_index[1]

    // ---------------- P0: scores, degrees, zero agg ----------------
    for (int idx = tg; idx < NN * INC; idx += GRID_B * BLK) agg[idx] = 0.f;

    if (gw < NN) {
        // pooling score for node gw: tanh(x[n]·p / ||p||)
        const float* xr = x + (size_t)gw * INC;
        float a = 0.f, pn = 0.f;
        for (int c = lane; c < INC; c += 64) { float pv = p[c]; a += xr[c] * pv; pn += pv * pv; }
        for (int o = 32; o; o >>= 1) { a += __shfl_xor(a, o, 64); pn += __shfl_xor(pn, o, 64); }
        if (lane == 0) score[gw] = tanhf(a / sqrtf(pn));
    } else if (gw < 2 * NN) {
        // in-degree (weighted) gather for node n; dis = rsqrt(deg + 1)
        int n = gw - NN;
        float d = 0.f;
        for (int e = lane; e < NE; e += 64) d += (col[e] == n) ? ew[e] : 0.f;
        for (int o = 32; o; o >>= 1) d += __shfl_xor(d, o, 64);
        if (lane == 0) dis[n] = rsqrtf(fmaxf(d + 1.0f, 1e-12f));
    }
    grid.sync();

    // ---------------- P1: redundant rank + GRU + x-space scatter ----------------
    if (t < NN) s_sc[t] = score[t];
    __syncthreads();
    if (t < NN) {
        float my = s_sc[t];
        int rank = 0;
        for (int j = 0; j < NN; ++j) {
            float o = s_sc[j];
            rank += (o > my || (o == my && j < t)) ? 1 : 0;   // stable descending
        }
        s_perm[rank] = t;
    }
    __syncthreads();

    // GRU: one wave per output element (i,j), ~4 jobs/wave
    for (int wid = gw; wid < NN * INC; wid += TOTW) {
        int i = wid / INC;
        int j = wid - i * INC;
        int pi = s_perm[i];
        float sc = s_sc[pi];
        const float* xr = x  + (size_t)pi * INC;
        const float* h0 = W0 + (size_t)i * INC;
        const float* wr = w_ih + (size_t)j * INC;
        const float* wz = wr + (size_t)INC * INC;
        const float* wn = wz + (size_t)INC * INC;
        const float* vr = w_hh + (size_t)j * INC;
        const float* vz = vr + (size_t)INC * INC;
        const float* vn = vz + (size_t)INC * INC;

        float sr = 0.f, szv = 0.f, an = 0.f, hn = 0.f;
        for (int c = lane; c < INC; c += 64) {
            float xv = xr[c] * sc;
            float hv = h0[c];
            sr  += xv * wr[c] + hv * vr[c];
            szv += xv * wz[c] + hv * vz[c];
            an  += xv * wn[c];
            hn  += hv * vn[c];
        }
        for (int o = 32; o; o >>= 1) {
            sr  += __shfl_xor(sr,  o, 64);
            szv += __shfl_xor(szv, o, 64);
            an  += __shfl_xor(an,  o, 64);
            hn  += __shfl_xor(hn,  o, 64);
        }
        if (lane == 0) {
            float r    = sigmf(sr  + b_ih[j]           + b_hh[j]);
            float z    = sigmf(szv + b_ih[INC + j]     + b_hh[INC + j]);
            float cand = tanhf(an + b_ih[2 * INC + j] + r * (hn + b_hh[2 * INC + j]));
            W[(size_t)i * INC + j] = (1.0f - z) * cand + z * h0[j];
        }
    }

    // x-space aggregation: agg[c] += norm * x[r]  (edges), + dc^2 * x[c] (self-loop)
    for (int idx = tg; idx < NE * INC; idx += GRID_B * BLK) {
        int e = idx / INC;
        int f = idx - e * INC;
        int r = row[e], c2 = col[e];
        float nrm = dis[r] * ew[e] * dis[c2];
        atomicAdd(&agg[(size_t)c2 * INC + f], nrm * x[(size_t)r * INC + f]);
    }
    for (int idx = tg; idx < NN * INC; idx += GRID_B * BLK) {
        int c2 = idx / INC;
        float dc = dis[c2];
        atomicAdd(&agg[idx], dc * dc * x[idx]);
    }
    grid.sync();

    // ---------------- P2: gcn = agg @ W + bias, ELU, final linear ----------------
    if (b < NN) {
        int c2 = b;
        if (t < NN) s_a[t] = agg[(size_t)c2 * INC + t];
        __syncthreads();
        if (t < NN) {
            float g = cb[t];
            for (int cc = 0; cc < INC; ++cc) g += s_a[cc] * W[(size_t)cc * INC + t];
            s_h[t] = (g > 0.f) ? g : expm1f(g);   // ELU
        }
        __syncthreads();
        for (int f = wv; f < OUTC; f += NWB) {
            const float* wrow = lw + (size_t)f * INC;
            float a2 = 0.f;
            for (int cc = lane; cc < INC; cc += 64) a2 += s_h[cc] * wrow[cc];
            for (int o = 32; o; o >>= 1) a2 += __shfl_xor(a2, o, 64);
            if (lane == 0) out[(size_t)c2 * OUTC + f] = a2 + lb[f];
        }
    }
}

extern "C" void kernel_launch(void* const* d_in, const int* in_sizes, int n_in,
                              void* d_out, int out_size, void* d_ws, size_t ws_size,
                              hipStream_t stream)
{
    const float* x   = (const float*)d_in[0];
    const int*   ei  = (const int*)d_in[1];
    const float* ew  = (const float*)d_in[2];
    const float* pp  = (const float*)d_in[3];
    const float* W0  = (const float*)d_in[4];
    const float* wih = (const float*)d_in[5];
    const float* whh = (const float*)d_in[6];
    const float* bih = (const float*)d_in[7];
    const float* bhh = (const float*)d_in[8];
    const float* cb  = (const float*)d_in[9];
    const float* lw  = (const float*)d_in[10];
    const float* lb  = (const float*)d_in[11];
    float* out = (float*)d_out;

    char* ws = (char*)d_ws;
    float* score = (float*)(ws + 0);                 // 129 f32
    float* dis   = (float*)(ws + 640);               // 129 f32
    float* W     = (float*)(ws + 1280);              // 129*129 f32
    float* agg   = (float*)(ws + 1280 + 69632);      // 129*129 f32

    void* args[] = { (void*)&x, (void*)&ei, (void*)&ew, (void*)&pp, (void*)&W0,
                     (void*)&wih, (void*)&whh, (void*)&bih, (void*)&bhh, (void*)&cb,
                     (void*)&lw, (void*)&lb, (void*)&out, (void*)&score, (void*)&dis,
                     (void*)&W, (void*)&agg };
    hipLaunchCooperativeKernel((const void*)k_all, dim3(GRID_B), dim3(BLK),
                               args, 0, stream);
}

// Round 5
// 65.443 us; speedup vs baseline: 1.5307x; 1.5307x over previous
//
#include <hip/hip_runtime.h>
#include <math.h>

#define NN 129
#define INC 129
#define OUTC 64
#define NE 4096

__device__ __forceinline__ float sigmf(float x) { return 1.0f / (1.0f + expf(-x)); }

// K1: blocks 0..128 -> dis[node]; blocks 129..257 -> score[node]
__global__ __launch_bounds__(256) void k_prep(
    const float* __restrict__ x, const float* __restrict__ p,
    const int* __restrict__ col, const float* __restrict__ ew,
    float* __restrict__ score, float* __restrict__ dis)
{
    __shared__ float red[4], red2[4];
    int b = blockIdx.x, t = threadIdx.x;
    int wv = t >> 6, lane = t & 63;
    if (b < NN) {
        float d = 0.f;
        for (int e = t; e < NE; e += 256) d += (col[e] == b) ? ew[e] : 0.f;
        for (int o = 32; o; o >>= 1) d += __shfl_xor(d, o, 64);
        if (lane == 0) red[wv] = d;
        __syncthreads();
        if (t == 0) {
            float s = 1.0f + red[0] + red[1] + red[2] + red[3];   // +1 self-loop
            dis[b] = rsqrtf(fmaxf(s, 1e-12f));
        }
    } else {
        int n = b - NN;
        float a = 0.f, pn = 0.f;
        if (t < INC) { float pv = p[t]; a = x[(size_t)n * INC + t] * pv; pn = pv * pv; }
        for (int o = 32; o; o >>= 1) { a += __shfl_xor(a, o, 64); pn += __shfl_xor(pn, o, 64); }
        if (lane == 0) { red[wv] = a; red2[wv] = pn; }
        __syncthreads();
        if (t == 0) {
            float dot = red[0] + red[1] + red[2] + red[3];
            float pnn = red2[0] + red2[1] + red2[2] + red2[3];
            score[n] = tanhf(dot / sqrtf(pnn));
        }
    }
}

// K2: per-block rank (stable descending) + one wave per GRU output element (i,j)
#define GRU_WPB 16
__global__ __launch_bounds__(1024) void k_gru(
    const float* __restrict__ x, const float* __restrict__ score,
    const float* __restrict__ W0,
    const float* __restrict__ w_ih, const float* __restrict__ w_hh,
    const float* __restrict__ b_ih, const float* __restrict__ b_hh,
    float* __restrict__ W)
{
    __shared__ float s_sc[NN];
    __shared__ int   s_perm[NN];
    int t = threadIdx.x, wv = t >> 6, lane = t & 63;
    if (t < NN) s_sc[t] = score[t];
    __syncthreads();
    if (t < NN) {
        float my = s_sc[t];
        int rank = 0;
        for (int j = 0; j < NN; ++j) {
            float o = s_sc[j];
            rank += (o > my || (o == my && j < t)) ? 1 : 0;
        }
        s_perm[rank] = t;
    }
    __syncthreads();

    int wid = blockIdx.x * GRU_WPB + wv;
    if (wid >= NN * INC) return;
    int i = wid / INC;
    int j = wid - i * INC;
    int pi = s_perm[i];
    float sc = s_sc[pi];
    const float* xr = x  + (size_t)pi * INC;
    const float* h0 = W0 + (size_t)i * INC;
    const float* wr = w_ih + (size_t)j * INC;
    const float* wz = wr + (size_t)INC * INC;
    const float* wn = wz + (size_t)INC * INC;
    const float* vr = w_hh + (size_t)j * INC;
    const float* vz = vr + (size_t)INC * INC;
    const float* vn = vz + (size_t)INC * INC;

    float sr = 0.f, szv = 0.f, an = 0.f, hn = 0.f;
    for (int c = lane; c < INC; c += 64) {
        float xv = xr[c] * sc;
        float hv = h0[c];
        sr  += xv * wr[c] + hv * vr[c];
        szv += xv * wz[c] + hv * vz[c];
        an  += xv * wn[c];
        hn  += hv * vn[c];
    }
    for (int o = 32; o; o >>= 1) {
        sr  += __shfl_xor(sr,  o, 64);
        szv += __shfl_xor(szv, o, 64);
        an  += __shfl_xor(an,  o, 64);
        hn  += __shfl_xor(hn,  o, 64);
    }
    if (lane == 0) {
        float r    = sigmf(sr  + b_ih[j]           + b_hh[j]);
        float z    = sigmf(szv + b_ih[INC + j]     + b_hh[INC + j]);
        float cand = tanhf(an + b_ih[2 * INC + j] + r * (hn + b_hh[2 * INC + j]));
        W[(size_t)i * INC + j] = (1.0f - z) * cand + z * h0[j];
    }
}

// K3: per output node c — edge list, x-space aggregation, agg@W+bias, ELU, linear
__global__ __launch_bounds__(1024) void k_gcn(
    const float* __restrict__ x, const int* __restrict__ row,
    const int* __restrict__ col, const float* __restrict__ ew,
    const float* __restrict__ dis, const float* __restrict__ W,
    const float* __restrict__ cb, const float* __restrict__ lw,
    const float* __restrict__ lb, float* __restrict__ out)
{
    __shared__ int   s_r[512];
    __shared__ float s_w[512];
    __shared__ int   s_cnt;
    __shared__ float s_dis[NN];
    __shared__ float s_a[NN];
    __shared__ float s_g[NN];
    __shared__ float s_h[NN];
    int c = blockIdx.x, t = threadIdx.x;
    int wv = t >> 6, lane = t & 63;

    if (t == 0) s_cnt = 0;
    if (t < NN) s_dis[t] = dis[t];
    __syncthreads();
    float dc = s_dis[c];

    // incoming-edge list of node c (avg ~32 entries)
    for (int e = t; e < NE; e += 1024) {
        if (col[e] == c) {
            int k = atomicAdd(&s_cnt, 1);
            if (k < 512) { s_r[k] = row[e]; s_w[k] = ew[e]; }
        }
    }
    if (t < NN) s_a[t] = dc * dc * x[(size_t)c * INC + t];   // self-loop term
    if (t < NN) s_g[t] = cb[t];
    __syncthreads();

    // wave-parallel aggregation: s_a[f] += norm_k * x[r_k][f]
    int cnt = min(s_cnt, 512);
    for (int k = wv; k < cnt; k += 16) {
        int r = s_r[k];
        float nrm = s_dis[r] * s_w[k] * dc;
        const float* xr = x + (size_t)r * INC;
        for (int f = lane; f < INC; f += 64) atomicAdd(&s_a[f], nrm * xr[f]);
    }
    __syncthreads();

    // wave-parallel matvec: s_g[f] += s_a[cc] * W[cc][f]  (W rows coalesced)
    for (int cc = wv; cc < NN; cc += 16) {
        float av = s_a[cc];
        const float* wrow = W + (size_t)cc * INC;
        for (int f = lane; f < INC; f += 64) atomicAdd(&s_g[f], av * wrow[f]);
    }
    __syncthreads();
    if (t < NN) { float g = s_g[t]; s_h[t] = (g > 0.f) ? g : expm1f(g); }   // ELU
    __syncthreads();

    // final linear: wave per output feature
    for (int f = wv; f < OUTC; f += 16) {
        const float* wrow = lw + (size_t)f * INC;
        float a = 0.f;
        for (int cc = lane; cc < INC; cc += 64) a += s_h[cc] * wrow[cc];
        for (int o = 32; o; o >>= 1) a += __shfl_xor(a, o, 64);
        if (lane == 0) out[(size_t)c * OUTC + f] = a + lb[f];
    }
}

extern "C" void kernel_launch(void* const* d_in, const int* in_sizes, int n_in,
                              void* d_out, int out_size, void* d_ws, size_t ws_size,
                              hipStream_t stream)
{
    const float* x   = (const float*)d_in[0];
    const int*   ei  = (const int*)d_in[1];
    const float* ew  = (const float*)d_in[2];
    const float* pp  = (const float*)d_in[3];
    const float* W0  = (const float*)d_in[4];
    const float* wih = (const float*)d_in[5];
    const float* whh = (const float*)d_in[6];
    const float* bih = (const float*)d_in[7];
    const float* bhh = (const float*)d_in[8];
    const float* cb  = (const float*)d_in[9];
    const float* lw  = (const float*)d_in[10];
    const float* lb  = (const float*)d_in[11];
    float* out = (float*)d_out;

    char* ws = (char*)d_ws;
    float* score = (float*)(ws + 0);          // 129 f32
    float* dis   = (float*)(ws + 640);        // 129 f32
    float* W     = (float*)(ws + 1280);       // 129*129 f32

    const int* row = ei;        // edge_index[0]
    const int* col = ei + NE;   // edge_index[1]

    k_prep<<<2 * NN, 256, 0, stream>>>(x, pp, col, ew, score, dis);

    int gru_blocks = (NN * INC + GRU_WPB - 1) / GRU_WPB;   // 1041
    k_gru<<<gru_blocks, 1024, 0, stream>>>(x, score, W0, wih, whh, bih, bhh, W);

    k_gcn<<<NN, 1024, 0, stream>>>(x, row, col, ew, dis, W, cb, lw, lb, out);
}

// Round 6
// 51.164 us; speedup vs baseline: 1.9579x; 1.2791x over previous
//
#include <hip/hip_runtime.h>
#include <math.h>

#define NN 129
#define INC 129
#define OUTC 64
#define NE 4096

__device__ __forceinline__ float sigmf(float x) { return 1.0f / (1.0f + expf(-x)); }

// D1: blocks 0..128 -> dis[node]; blocks 129..257 -> score[node]; all -> zero agg
__global__ __launch_bounds__(256) void k_prep(
    const float* __restrict__ x, const float* __restrict__ p,
    const int* __restrict__ col, const float* __restrict__ ew,
    float* __restrict__ score, float* __restrict__ dis, float* __restrict__ agg)
{
    __shared__ float red[4], red2[4];
    int b = blockIdx.x, t = threadIdx.x;
    int wv = t >> 6, lane = t & 63;

    int zidx = b * 256 + t;                 // 258*256 = 66048 >= 16641
    if (zidx < NN * INC) agg[zidx] = 0.f;

    if (b < NN) {
        float d = 0.f;
        for (int e = t; e < NE; e += 256) d += (col[e] == b) ? ew[e] : 0.f;
        for (int o = 32; o; o >>= 1) d += __shfl_xor(d, o, 64);
        if (lane == 0) red[wv] = d;
        __syncthreads();
        if (t == 0) {
            float s = 1.0f + red[0] + red[1] + red[2] + red[3];   // +1 self-loop
            dis[b] = rsqrtf(fmaxf(s, 1e-12f));
        }
    } else {
        int n = b - NN;
        float a = 0.f, pn = 0.f;
        if (t < INC) { float pv = p[t]; a = x[(size_t)n * INC + t] * pv; pn = pv * pv; }
        for (int o = 32; o; o >>= 1) { a += __shfl_xor(a, o, 64); pn += __shfl_xor(pn, o, 64); }
        if (lane == 0) { red[wv] = a; red2[wv] = pn; }
        __syncthreads();
        if (t == 0) {
            float dot = red[0] + red[1] + red[2] + red[3];
            float pnn = red2[0] + red2[1] + red2[2] + red2[3];
            score[n] = tanhf(dot / sqrtf(pnn));
        }
    }
}

// D2: blocks [0,1041) -> GRU (per-block rank + 1 wave per output element)
//     blocks [1041, ...) -> x-space scatter into agg (global atomics)
#define GRU_BLKS 1041
__global__ __launch_bounds__(1024) void k_mid(
    const float* __restrict__ x, const int* __restrict__ ei,
    const float* __restrict__ ew, const float* __restrict__ score,
    const float* __restrict__ dis, const float* __restrict__ W0,
    const float* __restrict__ w_ih, const float* __restrict__ w_hh,
    const float* __restrict__ b_ih, const float* __restrict__ b_hh,
    float* __restrict__ W, float* __restrict__ agg)
{
    int b = blockIdx.x, t = threadIdx.x;
    int wv = t >> 6, lane = t & 63;
    const int* row = ei;
    const int* col = ei + NE;

    if (b < GRU_BLKS) {
        __shared__ float s_sc[NN];
        __shared__ int   s_perm[NN];
        if (t < NN) s_sc[t] = score[t];
        __syncthreads();
        if (t < NN) {
            float my = s_sc[t];
            int rank = 0;
            for (int j = 0; j < NN; ++j) {
                float o = s_sc[j];
                rank += (o > my || (o == my && j < t)) ? 1 : 0;   // stable descending
            }
            s_perm[rank] = t;
        }
        __syncthreads();

        int wid = b * 16 + wv;
        if (wid >= NN * INC) return;
        int i = wid / INC;
        int j = wid - i * INC;
        int pi = s_perm[i];
        float sc = s_sc[pi];
        const float* xr = x  + (size_t)pi * INC;
        const float* h0 = W0 + (size_t)i * INC;
        const float* wr = w_ih + (size_t)j * INC;
        const float* wz = wr + (size_t)INC * INC;
        const float* wn = wz + (size_t)INC * INC;
        const float* vr = w_hh + (size_t)j * INC;
        const float* vz = vr + (size_t)INC * INC;
        const float* vn = vz + (size_t)INC * INC;

        float sr = 0.f, szv = 0.f, an = 0.f, hn = 0.f;
        for (int c = lane; c < INC; c += 64) {
            float xv = xr[c] * sc;
            float hv = h0[c];
            sr  += xv * wr[c] + hv * vr[c];
            szv += xv * wz[c] + hv * vz[c];
            an  += xv * wn[c];
            hn  += hv * vn[c];
        }
        for (int o = 32; o; o >>= 1) {
            sr  += __shfl_xor(sr,  o, 64);
            szv += __shfl_xor(szv, o, 64);
            an  += __shfl_xor(an,  o, 64);
            hn  += __shfl_xor(hn,  o, 64);
        }
        if (lane == 0) {
            float r    = sigmf(sr  + b_ih[j]           + b_hh[j]);
            float z    = sigmf(szv + b_ih[INC + j]     + b_hh[INC + j]);
            float cand = tanhf(an + b_ih[2 * INC + j] + r * (hn + b_hh[2 * INC + j]));
            W[(size_t)i * INC + j] = (1.0f - z) * cand + z * h0[j];
        }
    } else {
        int idx = (b - GRU_BLKS) * 1024 + t;
        if (idx < NE * INC) {
            int e = idx / INC;
            int f = idx - e * INC;
            int r = row[e], c2 = col[e];
            float nrm = dis[r] * ew[e] * dis[c2];
            atomicAdd(&agg[(size_t)c2 * INC + f], nrm * x[(size_t)r * INC + f]);
        } else {
            int idx2 = idx - NE * INC;
            if (idx2 < NN * INC) {
                int c2 = idx2 / INC;
                float dc = dis[c2];
                atomicAdd(&agg[idx2], dc * dc * x[idx2]);
            }
        }
    }
}

// D3: per node c — gcn = agg[c] @ W + bias (coalesced W rows), ELU, final linear
__global__ __launch_bounds__(256) void k_fin(
    const float* __restrict__ agg, const float* __restrict__ W,
    const float* __restrict__ cb, const float* __restrict__ lw,
    const float* __restrict__ lb, float* __restrict__ out)
{
    __shared__ float s_a[NN];
    __shared__ float s_h[NN];
    int c = blockIdx.x, t = threadIdx.x;
    int wv = t >> 6, lane = t & 63;

    if (t < NN) s_a[t] = agg[(size_t)c * INC + t];
    __syncthreads();
    if (t < NN) {
        float g = cb[t];
        for (int cc = 0; cc < INC; ++cc) g += s_a[cc] * W[(size_t)cc * INC + t];
        s_h[t] = (g > 0.f) ? g : expm1f(g);    // ELU
    }
    __syncthreads();
    for (int f = wv; f < OUTC; f += 4) {
        const float* wrow = lw + (size_t)f * INC;
        float a = 0.f;
        for (int cc = lane; cc < INC; cc += 64) a += s_h[cc] * wrow[cc];
        for (int o = 32; o; o >>= 1) a += __shfl_xor(a, o, 64);
        if (lane == 0) out[(size_t)c * OUTC + f] = a + lb[f];
    }
}

extern "C" void kernel_launch(void* const* d_in, const int* in_sizes, int n_in,
                              void* d_out, int out_size, void* d_ws, size_t ws_size,
                              hipStream_t stream)
{
    const float* x   = (const float*)d_in[0];
    const int*   ei  = (const int*)d_in[1];
    const float* ew  = (const float*)d_in[2];
    const float* pp  = (const float*)d_in[3];
    const float* W0  = (const float*)d_in[4];
    const float* wih = (const float*)d_in[5];
    const float* whh = (const float*)d_in[6];
    const float* bih = (const float*)d_in[7];
    const float* bhh = (const float*)d_in[8];
    const float* cb  = (const float*)d_in[9];
    const float* lw  = (const float*)d_in[10];
    const float* lb  = (const float*)d_in[11];
    float* out = (float*)d_out;

    char* ws = (char*)d_ws;
    float* score = (float*)(ws + 0);               // 129 f32
    float* dis   = (float*)(ws + 640);             // 129 f32
    float* W     = (float*)(ws + 1280);            // 129*129 f32
    float* agg   = (float*)(ws + 1280 + 69632);    // 129*129 f32

    const int* col = ei + NE;

    k_prep<<<2 * NN, 256, 0, stream>>>(x, pp, col, ew, score, dis, agg);

    int scat_items  = NE * INC + NN * INC;               // 545025
    int scat_blocks = (scat_items + 1023) / 1024;        // 533
    k_mid<<<GRU_BLKS + scat_blocks, 1024, 0, stream>>>(
        x, ei, ew, score, dis, W0, wih, whh, bih, bhh, W, agg);

    k_fin<<<NN, 256, 0, stream>>>(agg, W, cb, lw, lb, out);
}

// Round 7
// 44.587 us; speedup vs baseline: 2.2467x; 1.1475x over previous
//
#include <hip/hip_runtime.h>
#include <math.h>

#define NN 129
#define INC 129
#define OUTC 64
#define NE 4096

__device__ __forceinline__ float sigmf(float x) { return 1.0f / (1.0f + expf(-x)); }

// D1: block 0 -> all scores + stable descending perm (single block, like round 2);
//     blocks 1..129 -> dis[node]; all blocks -> zero agg
__global__ __launch_bounds__(256) void k_prep(
    const float* __restrict__ x, const float* __restrict__ p,
    const int* __restrict__ col, const float* __restrict__ ew,
    float* __restrict__ score, int* __restrict__ perm,
    float* __restrict__ dis, float* __restrict__ agg)
{
    int b = blockIdx.x, t = threadIdx.x;
    int wv = t >> 6, lane = t & 63;

    int zidx = b * 256 + t;                    // 130*256 = 33280 >= 16641
    if (zidx < NN * INC) agg[zidx] = 0.f;

    if (b == 0) {
        __shared__ float sp[INC];
        __shared__ float snorm;
        __shared__ float ssc[NN];
        if (t < INC) sp[t] = p[t];
        __syncthreads();
        if (t == 0) {
            float s = 0.f;
            for (int c = 0; c < INC; ++c) s += sp[c] * sp[c];
            snorm = sqrtf(s);
        }
        __syncthreads();
        if (t < NN) {
            float acc = 0.f;
            const float* xr = x + (size_t)t * INC;
            for (int c = 0; c < INC; ++c) acc += xr[c] * sp[c];
            float sc = tanhf(acc / snorm);
            ssc[t] = sc;
            score[t] = sc;
        }
        __syncthreads();
        if (t < NN) {
            float my = ssc[t];
            int rank = 0;
            for (int j = 0; j < NN; ++j) {
                float o = ssc[j];
                rank += (o > my || (o == my && j < t)) ? 1 : 0;   // stable descending
            }
            perm[rank] = t;
        }
    } else {
        __shared__ float red[4];
        int n = b - 1;
        float d = 0.f;
        for (int e = t; e < NE; e += 256) d += (col[e] == n) ? ew[e] : 0.f;
        for (int o = 32; o; o >>= 1) d += __shfl_xor(d, o, 64);
        if (lane == 0) red[wv] = d;
        __syncthreads();
        if (t == 0) {
            float s = 1.0f + red[0] + red[1] + red[2] + red[3];   // +1 self-loop
            dis[n] = rsqrtf(fmaxf(s, 1e-12f));
        }
    }
}

// D2: blocks [0, 4161) -> GRU, one wave per output element (round 2 pattern);
//     blocks [4161, 6291) -> flat x-space scatter into agg + self-loop term
#define GRU_BLKS 4161
__global__ __launch_bounds__(256) void k_mid(
    const float* __restrict__ x, const int* __restrict__ ei,
    const float* __restrict__ ew, const float* __restrict__ score,
    const int* __restrict__ perm, const float* __restrict__ dis,
    const float* __restrict__ W0,
    const float* __restrict__ w_ih, const float* __restrict__ w_hh,
    const float* __restrict__ b_ih, const float* __restrict__ b_hh,
    float* __restrict__ W, float* __restrict__ agg)
{
    int b = blockIdx.x, t = threadIdx.x;
    const int* row = ei;
    const int* col = ei + NE;

    if (b < GRU_BLKS) {
        int lane = t & 63;
        int wid = b * 4 + (t >> 6);
        if (wid >= NN * INC) return;
        int i = wid / INC;
        int j = wid - i * INC;
        int pi = perm[i];
        float sc = score[pi];
        const float* xr = x  + (size_t)pi * INC;
        const float* h0 = W0 + (size_t)i * INC;
        const float* wr = w_ih + (size_t)j * INC;
        const float* wz = wr + (size_t)INC * INC;
        const float* wn = wz + (size_t)INC * INC;
        const float* vr = w_hh + (size_t)j * INC;
        const float* vz = vr + (size_t)INC * INC;
        const float* vn = vz + (size_t)INC * INC;

        float sr = 0.f, szv = 0.f, an = 0.f, hn = 0.f;
        for (int c = lane; c < INC; c += 64) {
            float xv = xr[c] * sc;
            float hv = h0[c];
            sr  += xv * wr[c] + hv * vr[c];
            szv += xv * wz[c] + hv * vz[c];
            an  += xv * wn[c];
            hn  += hv * vn[c];
        }
        for (int o = 32; o; o >>= 1) {
            sr  += __shfl_xor(sr,  o, 64);
            szv += __shfl_xor(szv, o, 64);
            an  += __shfl_xor(an,  o, 64);
            hn  += __shfl_xor(hn,  o, 64);
        }
        if (lane == 0) {
            float r    = sigmf(sr  + b_ih[j]           + b_hh[j]);
            float z    = sigmf(szv + b_ih[INC + j]     + b_hh[INC + j]);
            float cand = tanhf(an + b_ih[2 * INC + j] + r * (hn + b_hh[2 * INC + j]));
            W[(size_t)i * INC + j] = (1.0f - z) * cand + z * h0[j];
        }
    } else {
        int idx = (b - GRU_BLKS) * 256 + t;
        if (idx < NE * INC) {
            int e = idx / INC;
            int f = idx - e * INC;
            int r = row[e], c2 = col[e];
            float nrm = dis[r] * ew[e] * dis[c2];
            atomicAdd(&agg[(size_t)c2 * INC + f], nrm * x[(size_t)r * INC + f]);
        } else {
            int idx2 = idx - NE * INC;
            if (idx2 < NN * INC) {
                int c2 = idx2 / INC;
                float dc = dis[c2];
                atomicAdd(&agg[idx2], dc * dc * x[idx2]);
            }
        }
    }
}

// D3: per node c — gcn = agg[c] @ W + bias (coalesced W rows), ELU, final linear
__global__ __launch_bounds__(256) void k_fin(
    const float* __restrict__ agg, const float* __restrict__ W,
    const float* __restrict__ cb, const float* __restrict__ lw,
    const float* __restrict__ lb, float* __restrict__ out)
{
    __shared__ float s_a[NN];
    __shared__ float s_h[NN];
    int c = blockIdx.x, t = threadIdx.x;
    int wv = t >> 6, lane = t & 63;

    if (t < NN) s_a[t] = agg[(size_t)c * INC + t];
    __syncthreads();
    if (t < NN) {
        float g = cb[t];
        for (int cc = 0; cc < INC; ++cc) g += s_a[cc] * W[(size_t)cc * INC + t];
        s_h[t] = (g > 0.f) ? g : expm1f(g);    // ELU
    }
    __syncthreads();
    for (int f = wv; f < OUTC; f += 4) {
        const float* wrow = lw + (size_t)f * INC;
        float a = 0.f;
        for (int cc = lane; cc < INC; cc += 64) a += s_h[cc] * wrow[cc];
        for (int o = 32; o; o >>= 1) a += __shfl_xor(a, o, 64);
        if (lane == 0) out[(size_t)c * OUTC + f] = a + lb[f];
    }
}

extern "C" void kernel_launch(void* const* d_in, const int* in_sizes, int n_in,
                              void* d_out, int out_size, void* d_ws, size_t ws_size,
                              hipStream_t stream)
{
    const float* x   = (const float*)d_in[0];
    const int*   ei  = (const int*)d_in[1];
    const float* ew  = (const float*)d_in[2];
    const float* pp  = (const float*)d_in[3];
    const float* W0  = (const float*)d_in[4];
    const float* wih = (const float*)d_in[5];
    const float* whh = (const float*)d_in[6];
    const float* bih = (const float*)d_in[7];
    const float* bhh = (const float*)d_in[8];
    const float* cb  = (const float*)d_in[9];
    const float* lw  = (const float*)d_in[10];
    const float* lb  = (const float*)d_in[11];
    float* out = (float*)d_out;

    char* ws = (char*)d_ws;
    float* score = (float*)(ws + 0);               // 129 f32
    int*   perm  = (int*)  (ws + 640);             // 129 i32
    float* dis   = (float*)(ws + 1280);            // 129 f32
    float* W     = (float*)(ws + 2048);            // 129*129 f32
    float* agg   = (float*)(ws + 2048 + 69632);    // 129*129 f32

    const int* col = ei + NE;

    k_prep<<<NN + 1, 256, 0, stream>>>(x, pp, col, ew, score, perm, dis, agg);

    int scat_items  = NE * INC + NN * INC;               // 545025
    int scat_blocks = (scat_items + 255) / 256;          // 2130
    k_mid<<<GRU_BLKS + scat_blocks, 256, 0, stream>>>(
        x, ei, ew, score, perm, dis, W0, wih, whh, bih, bhh, W, agg);

    k_fin<<<NN, 256, 0, stream>>>(agg, W, cb, lw, lb, out);
}